// Round 1
// baseline (145.519 us; speedup 1.0000x reference)
//
#include <hip/hip_runtime.h>

// ---------------------------------------------------------------------------
// metaLinear: y[t,o] = sum_j x2[t,j] * ( x1[t,:]@W[j*64+o,:] + bvec[j*64+o] )
//   T=16384 tokens, IN1=256, IN2=64 (j), OUT=64 (o).
// Strategy: bf16 MFMA (32x32x16), transposed tiles D[o][t] so the stage-2
// scalar x2[t,j] depends only on lane (col=lane&31=t). Bias via K-augmentation
// (K=272: x1 gains a constant-1 column, W gains a bvec column).
// W pre-converted to bf16 (padded rows) in d_ws by prep_w.
// ---------------------------------------------------------------------------

#define ROWE 280            // padded row length in bf16 elems; 140 dwords == 12 mod 32 -> conflict-free ds_read_b128
#define KAUG 272            // 256 + 1 (bias) + 15 zeros; 17 k-steps of 16
#define TILE_BYTES (64 * ROWE * 2)   // 35840 B per 64-row tile (contiguous in global AND lds)

typedef __bf16 bf16x8 __attribute__((ext_vector_type(8)));
typedef float  f32x16 __attribute__((ext_vector_type(16)));

static __device__ __forceinline__ unsigned short f2bf(float f) {
  union { float f; unsigned u; } v; v.f = f;
  unsigned r = v.u + 0x7FFFu + ((v.u >> 16) & 1u);   // RNE
  return (unsigned short)(r >> 16);
}

// Build augmented bf16 W in d_ws: Waug[c][0..255]=bf16(W[c][i]),
// Waug[c][256]=bf16(bvec[c]), Waug[c][257..279]=0.  4096 blocks x 256 thr.
__global__ void prep_w(const float* __restrict__ W, const float* __restrict__ bv,
                       unsigned short* __restrict__ Waug) {
  int c = blockIdx.x;       // 0..4095
  int t = threadIdx.x;      // 0..255
  Waug[(size_t)c * ROWE + t] = f2bf(W[(size_t)c * 256 + t]);
  if (t < ROWE - 256) {     // cols 256..279
    int col = 256 + t;
    float u = (col == 256) ? bv[c] : 0.0f;
    Waug[(size_t)c * ROWE + col] = f2bf(u);
  }
}

// Main fused kernel. 256 WGs x 256 threads (4 waves). WG g owns tokens
// [g*64, g*64+64). Wave w: t_half = w&1 (token 32-subtile), o_half = w>>1.
__global__ __launch_bounds__(256, 1)
void meta_main(const float* __restrict__ x1, const float* __restrict__ x2,
               const unsigned short* __restrict__ Waug, float* __restrict__ out) {
  // sW: union region — first holds the bf16 x1 tile (frags -> regs), then
  // re-used as the streamed W_j tile.  52224 B total static LDS.
  __shared__ unsigned short sW[64 * ROWE];
  __shared__ float sX2[64 * 64];          // x2 transposed: [j][t]

  const int tid  = threadIdx.x;
  const int lane = tid & 63;
  const int wv   = tid >> 6;
  const int th   = wv & 1;                // token half
  const int oh   = wv >> 1;               // output half
  const int l31  = lane & 31;
  const int lg   = lane >> 5;             // k-group within frag
  const long tile0 = (long)blockIdx.x * 64;

  // ---- stage x1 tile fp32 -> bf16 into sW (rows [t][ROWE]) ----
  {
    const float4* src = (const float4*)(x1 + tile0 * 256);
    #pragma unroll
    for (int it = 0; it < 16; ++it) {
      int fi4 = it * 256 + tid;           // coalesced float4 index
      float4 v = src[fi4];
      int token = fi4 >> 6;
      int col   = (fi4 & 63) * 4;
      ushort4 b;
      b.x = f2bf(v.x); b.y = f2bf(v.y); b.z = f2bf(v.z); b.w = f2bf(v.w);
      *(ushort4*)&sW[token * ROWE + col] = b;
    }
    if (tid < 64) {                       // augmented cols: [256]=1.0, rest 0
      ushort4 one; one.x = 0x3F80u; one.y = 0; one.z = 0; one.w = 0;
      ushort4 zz;  zz.x = 0; zz.y = 0; zz.z = 0; zz.w = 0;
      *(ushort4*)&sW[tid * ROWE + 256] = one;
      *(ushort4*)&sW[tid * ROWE + 260] = zz;
      *(ushort4*)&sW[tid * ROWE + 264] = zz;
      *(ushort4*)&sW[tid * ROWE + 268] = zz;
    }
    // ---- stage x2 transposed into sX2[j][t] (fp32, for stage-2) ----
    const float4* s2 = (const float4*)(x2 + tile0 * 64);
    #pragma unroll
    for (int it = 0; it < 4; ++it) {
      int fi4 = it * 256 + tid;
      float4 v = s2[fi4];
      int token = fi4 >> 4;
      int j0    = (fi4 & 15) * 4;
      sX2[(j0 + 0) * 64 + token] = v.x;
      sX2[(j0 + 1) * 64 + token] = v.y;
      sX2[(j0 + 2) * 64 + token] = v.z;
      sX2[(j0 + 3) * 64 + token] = v.w;
    }
  }
  __syncthreads();

  // ---- load x1 B-frags once: B[k=i][n=t], t = 32*th + l31, k = ks*16 + lg*8 ----
  bf16x8 bfrag[17];
  {
    const unsigned short* base = &sW[(32 * th + l31) * ROWE + lg * 8];
    #pragma unroll
    for (int ks = 0; ks < 17; ++ks)
      bfrag[ks] = *(const bf16x8*)(base + ks * 16);
  }
  __syncthreads();                         // x1 fully consumed from sW

  f32x16 yacc;
  #pragma unroll
  for (int r = 0; r < 16; ++r) yacc[r] = 0.0f;

  const unsigned short* abase = &sW[(32 * oh + l31) * ROWE + lg * 8];

  for (int j = 0; j < 64; ++j) {
    // ---- stage W_j tile (64 rows, contiguous 35840 B) global->LDS, 16B/lane ----
    {
      const unsigned char* g = (const unsigned char*)(Waug + (size_t)j * 64 * ROWE);
      unsigned char* l = (unsigned char*)sW;
      #pragma unroll
      for (int c = 0; c < 9; ++c) {
        int off = tid * 16 + c * 4096;
        if (off < TILE_BYTES)              // last chunk: waves 0-2 only (whole waves)
          __builtin_amdgcn_global_load_lds(
              (const __attribute__((address_space(1))) unsigned int*)(g + off),
              (__attribute__((address_space(3))) unsigned int*)(l + off),
              16, 0, 0);
      }
    }
    __syncthreads();                       // drains vmcnt -> W_j resident

    float x2s = sX2[j * 64 + 32 * th + l31];   // x2[t][j], t = col of D

    // ---- stage 1: w^T[o][t] = sum_k Waug[j*64+o][k] * x1aug[t][k], K split 8/9 ----
    f32x16 wlo, whi;
    #pragma unroll
    for (int r = 0; r < 16; ++r) { wlo[r] = 0.0f; whi[r] = 0.0f; }
    #pragma unroll
    for (int ks = 0; ks < 8; ++ks) {
      bf16x8 af = *(const bf16x8*)(abase + ks * 16);
      wlo = __builtin_amdgcn_mfma_f32_32x32x16_bf16(af, bfrag[ks], wlo, 0, 0, 0);
    }
    #pragma unroll
    for (int ks = 8; ks < 17; ++ks) {
      bf16x8 af = *(const bf16x8*)(abase + ks * 16);
      whi = __builtin_amdgcn_mfma_f32_32x32x16_bf16(af, bfrag[ks], whi, 0, 0, 0);
    }

    // ---- stage 2: y[t][o] += x2[t][j] * w[t][o]  (fp32) ----
    #pragma unroll
    for (int r = 0; r < 16; ++r)
      yacc[r] += x2s * (wlo[r] + whi[r]);

    __syncthreads();                       // all waves done reading sW before next stage
  }

  // ---- epilogue: D row = o_local = (r&3) + 8*(r>>2) + 4*lg, col = t = l31 ----
  float* yout = out + (tile0 + 32 * th + l31) * 64 + oh * 32;
  #pragma unroll
  for (int r = 0; r < 16; ++r) {
    int ol = (r & 3) + 8 * (r >> 2) + 4 * lg;
    yout[ol] = yacc[r];
  }
}

extern "C" void kernel_launch(void* const* d_in, const int* in_sizes, int n_in,
                              void* d_out, int out_size, void* d_ws, size_t ws_size,
                              hipStream_t stream) {
  const float* x1 = (const float*)d_in[0];   // (4,4096,256) f32
  const float* x2 = (const float*)d_in[1];   // (4,4096,64)  f32
  const float* W  = (const float*)d_in[2];   // (4096,256)   f32
  const float* bv = (const float*)d_in[3];   // (4096,)      f32
  float* y = (float*)d_out;                  // (4,4096,64)  f32
  unsigned short* Waug = (unsigned short*)d_ws;   // 4096*280*2 = 2,293,760 B

  prep_w<<<4096, 256, 0, stream>>>(W, bv, Waug);
  meta_main<<<256, 256, 0, stream>>>(x1, x2, Waug, y);
}

// Round 2
// 113.506 us; speedup vs baseline: 1.2820x; 1.2820x over previous
//
#include <hip/hip_runtime.h>

// ---------------------------------------------------------------------------
// metaLinear: y[t,o] = sum_j x2[t,j] * ( x1[t,:]@W[j*64+o,:] + bvec[j*64+o] )
//   T=16384, IN1=256, IN2=64 (j), OUT=64 (o).
// Round 2: W pre-shuffled into MFMA A-fragment order (prep_w), so the main
// j-loop has NO barriers and NO LDS staging: per j per wave, 17 coalesced
// global_load_dwordx4 (register double-buffered, L2-resident) + 17 MFMA +
// 32 VALU. Bias via K-augmentation (frag 16 = bvec column).
// ---------------------------------------------------------------------------

#define NFRAG 17                       // 16 data k-steps + 1 bias k-step
#define FRAG_SHORTS 512                // 64 lanes * 8 bf16
#define OH_SHORTS (NFRAG * FRAG_SHORTS)    // 8704 shorts per (j, o-half)
#define J_SHORTS  (2 * OH_SHORTS)          // 17408 shorts per j

typedef __bf16 bf16x8 __attribute__((ext_vector_type(8)));
typedef float  f32x16 __attribute__((ext_vector_type(16)));

static __device__ __forceinline__ unsigned short f2bf(float f) {
  union { float f; unsigned u; } v; v.f = f;
  unsigned r = v.u + 0x7FFFu + ((v.u >> 16) & 1u);   // RNE
  return (unsigned short)(r >> 16);
}

// Pre-shuffle W+bias into fragment order:
//   Wf[((j*2+oh)*17 + ks)*512 + lane*8 + e] =
//       bf16( Waug[row = 64j+32oh+(lane&31)][col = 16ks + 8*(lane>>5) + e] )
// where Waug col 256 = bvec, cols 257.. = 0 (ks=16 is the bias frag).
// Thread (r, ks): coalesced 64B row read, two 16B stores (lg=0 / lg=1).
__global__ void prep_w(const float* __restrict__ W, const float* __restrict__ bv,
                       unsigned short* __restrict__ Wf) {
  int idx = blockIdx.x * 256 + threadIdx.x;   // 65536 total
  int r  = idx >> 4;                          // W row 0..4095
  int ks = idx & 15;                          // data k-step 0..15
  int j   = r >> 6;
  int o   = r & 63;
  int oh  = o >> 5;
  int l31 = o & 31;
  size_t fb = ((size_t)(j * 2 + oh) * NFRAG + ks) * FRAG_SHORTS;

  const float4* row = (const float4*)(W + (size_t)r * 256 + ks * 16);
  float4 v0 = row[0], v1 = row[1], v2 = row[2], v3 = row[3];
  ushort4 lo0, lo1, hi0, hi1;
  lo0.x = f2bf(v0.x); lo0.y = f2bf(v0.y); lo0.z = f2bf(v0.z); lo0.w = f2bf(v0.w);
  lo1.x = f2bf(v1.x); lo1.y = f2bf(v1.y); lo1.z = f2bf(v1.z); lo1.w = f2bf(v1.w);
  hi0.x = f2bf(v2.x); hi0.y = f2bf(v2.y); hi0.z = f2bf(v2.z); hi0.w = f2bf(v2.w);
  hi1.x = f2bf(v3.x); hi1.y = f2bf(v3.y); hi1.z = f2bf(v3.z); hi1.w = f2bf(v3.w);
  *(ushort4*)&Wf[fb + l31 * 8 + 0] = lo0;            // lg=0, cols 16ks..+3
  *(ushort4*)&Wf[fb + l31 * 8 + 4] = lo1;            //        cols +4..+7
  *(ushort4*)&Wf[fb + 256 + l31 * 8 + 0] = hi0;      // lg=1, cols +8..+11
  *(ushort4*)&Wf[fb + 256 + l31 * 8 + 4] = hi1;      //        cols +12..+15

  if (ks == 0) {                                     // bias frag (ks=16)
    size_t bb = ((size_t)(j * 2 + oh) * NFRAG + 16) * FRAG_SHORTS;
    ushort4 b0; b0.x = f2bf(bv[r]); b0.y = 0; b0.z = 0; b0.w = 0;
    ushort4 zz; zz.x = 0; zz.y = 0; zz.z = 0; zz.w = 0;
    *(ushort4*)&Wf[bb + l31 * 8 + 0] = b0;           // lg=0: col 256 = bias
    *(ushort4*)&Wf[bb + l31 * 8 + 4] = zz;
    *(ushort4*)&Wf[bb + 256 + l31 * 8 + 0] = zz;     // lg=1: zeros
    *(ushort4*)&Wf[bb + 256 + l31 * 8 + 4] = zz;
  }
}

// Main fused kernel. 256 WGs x 256 threads (4 waves). WG g owns tokens
// [g*64, g*64+64). Wave w: th = w&1 (token 32-subtile), oh = w>>1.
__global__ __launch_bounds__(256, 1)
void meta_main(const float* __restrict__ x1, const float* __restrict__ x2,
               const unsigned short* __restrict__ Wf, float* __restrict__ out) {
  __shared__ unsigned short sX1[64 * 280];   // bf16 x1 tile, +pad rows
  __shared__ float sX2[64 * 64];             // x2 transposed: [j][t]

  const int tid  = threadIdx.x;
  const int lane = tid & 63;
  const int wv   = tid >> 6;
  const int th   = wv & 1;
  const int oh   = wv >> 1;
  const int l31  = lane & 31;
  const int lg   = lane >> 5;
  const long tile0 = (long)blockIdx.x * 64;

  // ---- stage x1 tile fp32 -> bf16 into sX1 ----
  {
    const float4* src = (const float4*)(x1 + tile0 * 256);
    #pragma unroll
    for (int it = 0; it < 16; ++it) {
      int fi4 = it * 256 + tid;
      float4 v = src[fi4];
      int token = fi4 >> 6;
      int col   = (fi4 & 63) * 4;
      ushort4 b;
      b.x = f2bf(v.x); b.y = f2bf(v.y); b.z = f2bf(v.z); b.w = f2bf(v.w);
      *(ushort4*)&sX1[token * 280 + col] = b;
    }
    if (tid < 64) {                          // augmented cols: [256]=1.0, rest 0
      ushort4 one; one.x = 0x3F80u; one.y = 0; one.z = 0; one.w = 0;
      ushort4 zz;  zz.x = 0; zz.y = 0; zz.z = 0; zz.w = 0;
      *(ushort4*)&sX1[tid * 280 + 256] = one;
      *(ushort4*)&sX1[tid * 280 + 260] = zz;
      *(ushort4*)&sX1[tid * 280 + 264] = zz;
      *(ushort4*)&sX1[tid * 280 + 268] = zz;
    }
    const float4* s2 = (const float4*)(x2 + tile0 * 64);
    #pragma unroll
    for (int it = 0; it < 4; ++it) {
      int fi4 = it * 256 + tid;
      float4 v = s2[fi4];
      int token = fi4 >> 4;
      int j0    = (fi4 & 15) * 4;
      sX2[(j0 + 0) * 64 + token] = v.x;
      sX2[(j0 + 1) * 64 + token] = v.y;
      sX2[(j0 + 2) * 64 + token] = v.z;
      sX2[(j0 + 3) * 64 + token] = v.w;
    }
  }
  __syncthreads();                            // only barrier in the kernel

  // ---- x1 B-frags, register-resident for the whole j-loop ----
  bf16x8 bfrag[NFRAG];
  {
    const unsigned short* base = &sX1[(32 * th + l31) * 280 + lg * 8];
    #pragma unroll
    for (int ks = 0; ks < NFRAG; ++ks)
      bfrag[ks] = *(const bf16x8*)(base + ks * 16);
  }

  f32x16 yacc;
  #pragma unroll
  for (int r = 0; r < 16; ++r) yacc[r] = 0.0f;

  const int tt = 32 * th + l31;               // this lane's token column
  const unsigned short* wbase = Wf + (size_t)oh * OH_SHORTS + lane * 8;

  // ---- register double-buffered W frags; no barriers, no LDS in loop ----
  bf16x8 wa[NFRAG], wb[NFRAG];
  #pragma unroll
  for (int ks = 0; ks < NFRAG; ++ks)
    wa[ks] = *(const bf16x8*)(wbase + ks * FRAG_SHORTS);

  for (int j = 0; j < 64; j += 2) {
    // prefetch j+1 into wb
    if (j + 1 < 64) {
      const unsigned short* p = wbase + (size_t)(j + 1) * J_SHORTS;
      #pragma unroll
      for (int ks = 0; ks < NFRAG; ++ks)
        wb[ks] = *(const bf16x8*)(p + ks * FRAG_SHORTS);
    }
    {
      float x2s = sX2[j * 64 + tt];
      f32x16 wlo, whi;
      #pragma unroll
      for (int r = 0; r < 16; ++r) { wlo[r] = 0.0f; whi[r] = 0.0f; }
      #pragma unroll
      for (int ks = 0; ks < 8; ++ks)
        wlo = __builtin_amdgcn_mfma_f32_32x32x16_bf16(wa[ks], bfrag[ks], wlo, 0, 0, 0);
      #pragma unroll
      for (int ks = 8; ks < NFRAG; ++ks)
        whi = __builtin_amdgcn_mfma_f32_32x32x16_bf16(wa[ks], bfrag[ks], whi, 0, 0, 0);
      #pragma unroll
      for (int r = 0; r < 16; ++r)
        yacc[r] += x2s * (wlo[r] + whi[r]);
    }
    // prefetch j+2 into wa
    if (j + 2 < 64) {
      const unsigned short* p = wbase + (size_t)(j + 2) * J_SHORTS;
      #pragma unroll
      for (int ks = 0; ks < NFRAG; ++ks)
        wa[ks] = *(const bf16x8*)(p + ks * FRAG_SHORTS);
    }
    {
      float x2s = sX2[(j + 1) * 64 + tt];
      f32x16 wlo, whi;
      #pragma unroll
      for (int r = 0; r < 16; ++r) { wlo[r] = 0.0f; whi[r] = 0.0f; }
      #pragma unroll
      for (int ks = 0; ks < 8; ++ks)
        wlo = __builtin_amdgcn_mfma_f32_32x32x16_bf16(wb[ks], bfrag[ks], wlo, 0, 0, 0);
      #pragma unroll
      for (int ks = 8; ks < NFRAG; ++ks)
        whi = __builtin_amdgcn_mfma_f32_32x32x16_bf16(wb[ks], bfrag[ks], whi, 0, 0, 0);
      #pragma unroll
      for (int r = 0; r < 16; ++r)
        yacc[r] += x2s * (wlo[r] + whi[r]);
    }
  }

  // ---- epilogue: D row = o_local = (r&3) + 8*(r>>2) + 4*lg, col = t = l31 ----
  float* yout = out + (tile0 + tt) * 64 + oh * 32;
  #pragma unroll
  for (int r = 0; r < 16; ++r) {
    int ol = (r & 3) + 8 * (r >> 2) + 4 * lg;
    yout[ol] = yacc[r];
  }
}

extern "C" void kernel_launch(void* const* d_in, const int* in_sizes, int n_in,
                              void* d_out, int out_size, void* d_ws, size_t ws_size,
                              hipStream_t stream) {
  const float* x1 = (const float*)d_in[0];   // (4,4096,256) f32
  const float* x2 = (const float*)d_in[1];   // (4,4096,64)  f32
  const float* W  = (const float*)d_in[2];   // (4096,256)   f32
  const float* bv = (const float*)d_in[3];   // (4096,)      f32
  float* y = (float*)d_out;                  // (4,4096,64)  f32
  unsigned short* Wf = (unsigned short*)d_ws;  // 64*17408*2 = 2,228,224 B

  prep_w<<<256, 256, 0, stream>>>(W, bv, Wf);
  meta_main<<<256, 256, 0, stream>>>(x1, x2, Wf, y);
}